// Round 1
// 303.605 us; speedup vs baseline: 1.0122x; 1.0122x over previous
//
#include <hip/hip_runtime.h>
#include <hip/hip_bf16.h>
#include <stdint.h>

typedef unsigned short u16;
using bf16x8 = __attribute__((ext_vector_type(8))) __bf16;
using f32x4  = __attribute__((ext_vector_type(4))) float;

// fp32 -> bf16 (round-to-nearest-even), as raw bits
__device__ __forceinline__ u16 f2bf(float f) {
    union { float f; unsigned u; } a; a.f = f;
    unsigned u = a.u;
    u += 0x7fffu + ((u >> 16) & 1u);
    return (u16)(u >> 16);
}
__device__ __forceinline__ float bf2f(unsigned bits_hi16) {
    union { unsigned u; float f; } a; a.u = bits_hi16; return a.f;
}

// async global->LDS, 16 bytes per lane (global_load_lds_dwordx4)
__device__ __forceinline__ void gload_lds16(const void* g, void* l) {
    __builtin_amdgcn_global_load_lds(
        (const __attribute__((address_space(1))) void*)g,
        (__attribute__((address_space(3))) void*)l, 16, 0, 0);
}

// Bijective XCD-aware swizzle (T1): HW assigns XCD = flat_id % 8 (round-robin).
// Remap so each XCD gets a CONTIGUOUS chunk of the grid -> neighboring tiles
// that share operand panels land on the same per-XCD L2.
// Requires nwg % 8 == 0 (all users here have nwg = 512).
__device__ __forceinline__ void xcd_swz(int nx, int ny, int& x, int& y, int& z) {
    const int flat = (int)blockIdx.x + nx * ((int)blockIdx.y + ny * (int)blockIdx.z);
    const int cpx = (nx * ny * (int)gridDim.z) >> 3;  // chunk per XCD
    const int s = (flat & 7) * cpx + (flat >> 3);
    x = s % nx;
    const int t = s / nx;
    y = t % ny;
    z = t / ny;
}

// ---------------------------------------------------------------------------
// Shared 128x128-tile bf16 GEMM core, C = A @ B^T
//   A:[M x lda] row-major (uses kLen cols), B:[N x ldb] row-major.
// 256 threads = 4 waves in 2x2; each wave does 64x64 via 4x4 tiles of 16x16x32.
// BK=64 per barrier: two side-by-side 128x32 LDS stages (same proven layout),
// 8 global_load_lds(16B) + one barrier pair per 64-K. LDS 16 KB per operand.
// kLen must be a multiple of 64.
// ---------------------------------------------------------------------------
__device__ __forceinline__ void gemm_core(const u16* __restrict__ A,
                                          const u16* __restrict__ B,
                                          int lda, int ldb, int kLen,
                                          int bm, int bn,
                                          u16* sA, u16* sB,
                                          f32x4 acc[4][4])
{
    const int tid  = threadIdx.x;
    const int lane = tid & 63;
    const int wm   = (tid >> 7) & 1;
    const int wn   = (tid >> 6) & 1;

    // staging (per 128x32 stage): thread t -> row=t>>2 (0..63), col8=(t&3)*8
    const u16* Ag0 = A + (long)(bm * 128 + (tid >> 2)) * lda + (tid & 3) * 8;
    const u16* Ag1 = Ag0 + (long)64 * lda;
    const u16* Bg0 = B + (long)(bn * 128 + (tid >> 2)) * ldb + (tid & 3) * 8;
    const u16* Bg1 = Bg0 + (long)64 * ldb;
    u16* la = sA + tid * 8;
    u16* lb = sB + tid * 8;

    // fragment read base within a stage: A[m=lane&15][k=(lane>>4)*8 + j]
    const int rfo = (wm * 64 + (lane & 15)) * 32 + (lane >> 4) * 8;
    const int rfoB = (wn * 64 + (lane & 15)) * 32 + (lane >> 4) * 8;

    for (int k0 = 0; k0 < kLen; k0 += 64) {
        // stage 0: k [k0, k0+32)
        gload_lds16(Ag0 + k0, la);
        gload_lds16(Ag1 + k0, la + 2048);
        gload_lds16(Bg0 + k0, lb);
        gload_lds16(Bg1 + k0, lb + 2048);
        // stage 1: k [k0+32, k0+64)
        gload_lds16(Ag0 + k0 + 32, la + 4096);
        gload_lds16(Ag1 + k0 + 32, la + 6144);
        gload_lds16(Bg0 + k0 + 32, lb + 4096);
        gload_lds16(Bg1 + k0 + 32, lb + 6144);
        __syncthreads();
#pragma unroll
        for (int h = 0; h < 2; h++) {
            const u16* ra = sA + h * 4096 + rfo;
            const u16* rb = sB + h * 4096 + rfoB;
            bf16x8 af[4], bfr[4];
#pragma unroll
            for (int i = 0; i < 4; i++) af[i]  = *(const bf16x8*)(ra + i * 512);
#pragma unroll
            for (int i = 0; i < 4; i++) bfr[i] = *(const bf16x8*)(rb + i * 512);
#pragma unroll
            for (int mi = 0; mi < 4; mi++)
#pragma unroll
                for (int ni = 0; ni < 4; ni++)
                    acc[mi][ni] = __builtin_amdgcn_mfma_f32_16x16x32_bf16(
                        af[mi], bfr[ni], acc[mi][ni], 0, 0, 0);
        }
        __syncthreads();
    }
}

// ---------------------------------------------------------------------------
// Kernel 1: fp32 -> bf16 casts for q,k,v (nqkv each) and Wq,Wk,Wv (nw each)
// ---------------------------------------------------------------------------
__global__ __launch_bounds__(256)
void cast6(const float* __restrict__ q, const float* __restrict__ k,
           const float* __restrict__ v, const float* __restrict__ wq,
           const float* __restrict__ wk, const float* __restrict__ wv,
           u16* __restrict__ qb, u16* __restrict__ kb, u16* __restrict__ vb,
           u16* __restrict__ wqb, u16* __restrict__ wkb, u16* __restrict__ wvb,
           int nqkv, int nw)
{
    const int z = blockIdx.y;
    const float* s; u16* d; int n;
    switch (z) {
        case 0:  s = q;  d = qb;  n = nqkv; break;
        case 1:  s = k;  d = kb;  n = nqkv; break;
        case 2:  s = v;  d = vb;  n = nqkv; break;
        case 3:  s = wq; d = wqb; n = nw;   break;
        case 4:  s = wk; d = wkb; n = nw;   break;
        default: s = wv; d = wvb; n = nw;   break;
    }
    long i = ((long)blockIdx.x * 256 + threadIdx.x) * 8;
    if (i >= n) return;
    float4 a = *(const float4*)(s + i);
    float4 b = *(const float4*)(s + i + 4);
    ushort4 o0, o1;
    o0.x = f2bf(a.x); o0.y = f2bf(a.y); o0.z = f2bf(a.z); o0.w = f2bf(a.w);
    o1.x = f2bf(b.x); o1.y = f2bf(b.y); o1.z = f2bf(b.z); o1.w = f2bf(b.w);
    *(ushort4*)(d + i)     = o0;
    *(ushort4*)(d + i + 4) = o1;
}

// ---------------------------------------------------------------------------
// Kernel 2: QK projections (launched with gridDim.z == 2; z=2 path unused).
//   z=0: qp = (q @ Wq^T + bq)*scale   z=1: kp = k @ Wk^T + bk
// XCD-swizzled: each XCD gets a contiguous chunk of M-tiles for one z ->
// A-rows are XCD-exclusive, B (2 MB weights) resident per XCD.
// ---------------------------------------------------------------------------
__global__ __launch_bounds__(256, 2)
void proj_gemm(const u16* __restrict__ qb, const u16* __restrict__ kb,
               const u16* __restrict__ vb, const u16* __restrict__ wqb,
               const u16* __restrict__ wkb, const u16* __restrict__ wvb,
               const float* __restrict__ bq, const float* __restrict__ bk,
               const float* __restrict__ bv,
               u16* __restrict__ qp, u16* __restrict__ kp, u16* __restrict__ vpT)
{
    __shared__ __align__(16) u16 sA[8192];
    __shared__ __align__(16) u16 sB[8192];
    int bx, by, bz;
    xcd_swz(8, 32, bx, by, bz);
    const int z = bz;
    const u16* A = (z == 0) ? qb : (z == 1) ? kb : vb;
    const u16* B = (z == 0) ? wqb : (z == 1) ? wkb : wvb;
    const float* bias = (z == 0) ? bq : (z == 1) ? bk : bv;
    u16* OUT = (z == 0) ? qp : (z == 1) ? kp : vpT;
    const float scale = (z == 0) ? 0.03125f : 1.0f;  // 1024^-0.5

    f32x4 acc[4][4] = {};
    gemm_core(A, B, 1024, 1024, 1024, by, bx, sA, sB, acc);

    const int lane = threadIdx.x & 63;
    const int wm   = (threadIdx.x >> 7) & 1;
    const int wn   = (threadIdx.x >> 6) & 1;
    const int m0 = by * 128 + wm * 64 + ((lane >> 4) << 2);
    const int n0 = bx * 128 + wn * 64 + (lane & 15);
#pragma unroll
    for (int mi = 0; mi < 4; mi++)
#pragma unroll
        for (int ni = 0; ni < 4; ni++) {
            const int gm = m0 + mi * 16;
            const int gn = n0 + ni * 16;
            const float bb = bias[gn];
#pragma unroll
            for (int r = 0; r < 4; r++) {
                float val = (acc[mi][ni][r] + bb) * scale;
                if (z < 2) OUT[(long)(gm + r) * 1024 + gn] = f2bf(val);
                else       OUT[(long)gn * 4096 + gm + r]   = f2bf(val);
            }
        }
}

// ---------------------------------------------------------------------------
// Kernel 2b: vpT = Wv @ v^T + bv (per-row)  [1024 x 4096] -- transpose-free.
// A = Wv [1024x1024], B = v [4096x1024], C[m,n] = vp[n,m]. Coalesced stores.
// Grid (32, 8): bn = blockIdx.x (N tiles), bm = blockIdx.y (M tiles).
// No swizzle: default XCD = x%8 already column-partitions B (1 MB/XCD
// resident) while streaming the small Wv (2 MB) -- already L2-friendly.
// ---------------------------------------------------------------------------
__global__ __launch_bounds__(256, 2)
void vproj_gemm(const u16* __restrict__ wvb, const u16* __restrict__ vb,
                const float* __restrict__ bv, u16* __restrict__ vpT)
{
    __shared__ __align__(16) u16 sA[8192];
    __shared__ __align__(16) u16 sB[8192];
    f32x4 acc[4][4] = {};
    gemm_core(wvb, vb, 1024, 1024, 1024, blockIdx.y, blockIdx.x, sA, sB, acc);

    const int lane = threadIdx.x & 63;
    const int wm   = (threadIdx.x >> 7) & 1;
    const int wn   = (threadIdx.x >> 6) & 1;
    const int m0 = blockIdx.y * 128 + wm * 64 + ((lane >> 4) << 2);
    const int n0 = blockIdx.x * 128 + wn * 64 + (lane & 15);
#pragma unroll
    for (int mi = 0; mi < 4; mi++)
#pragma unroll
        for (int ni = 0; ni < 4; ni++) {
            const int gm = m0 + mi * 16;
            const int gn = n0 + ni * 16;
#pragma unroll
            for (int r = 0; r < 4; r++)
                vpT[(long)(gm + r) * 4096 + gn] = f2bf(acc[mi][ni][r] + bv[gm + r]);
        }
}

// ---------------------------------------------------------------------------
// Kernel 3: scores = qp @ kp^T  -> bf16 S, M=N=4096, K=1024
// No swizzle: per-XCD fetch is ~72 MB under either mapping (symmetric M/N);
// kernel runs at ~2.3 TB/s effective -> structure-bound, not BW-bound.
// ---------------------------------------------------------------------------
__global__ __launch_bounds__(256, 2)
void score_gemm(const u16* __restrict__ qp, const u16* __restrict__ kp,
                u16* __restrict__ S)
{
    __shared__ __align__(16) u16 sA[8192];
    __shared__ __align__(16) u16 sB[8192];
    f32x4 acc[4][4] = {};
    gemm_core(qp, kp, 1024, 1024, 1024, blockIdx.y, blockIdx.x, sA, sB, acc);

    const int lane = threadIdx.x & 63;
    const int wm   = (threadIdx.x >> 7) & 1;
    const int wn   = (threadIdx.x >> 6) & 1;
    const int m0 = blockIdx.y * 128 + wm * 64 + ((lane >> 4) << 2);
    const int n0 = blockIdx.x * 128 + wn * 64 + (lane & 15);
#pragma unroll
    for (int mi = 0; mi < 4; mi++)
#pragma unroll
        for (int ni = 0; ni < 4; ni++) {
            const int gm = m0 + mi * 16;
            const int gn = n0 + ni * 16;
#pragma unroll
            for (int r = 0; r < 4; r++)
                S[(long)(gm + r) * 4096 + gn] = f2bf(acc[mi][ni][r]);
        }
}

// ---------------------------------------------------------------------------
// Kernel 4: att = softmax(S_bf16, axis=-1) + bias, cast to bf16. Block per row.
// ---------------------------------------------------------------------------
__global__ __launch_bounds__(256)
void softmax_bias(const u16* __restrict__ S, const float* __restrict__ bias,
                  u16* __restrict__ att)
{
    const long row = blockIdx.x;
    const int tid = threadIdx.x;
    const u16* srow = S + row * 4096 + tid * 16;

    float v[16];
    {
        uint4 a = *(const uint4*)(srow);
        uint4 b = *(const uint4*)(srow + 8);
        unsigned w[8] = {a.x, a.y, a.z, a.w, b.x, b.y, b.z, b.w};
#pragma unroll
        for (int i = 0; i < 8; i++) {
            v[2 * i]     = bf2f(w[i] << 16);
            v[2 * i + 1] = bf2f(w[i] & 0xffff0000u);
        }
    }
    float mx = v[0];
#pragma unroll
    for (int i = 1; i < 16; i++) mx = fmaxf(mx, v[i]);
#pragma unroll
    for (int o = 32; o >= 1; o >>= 1) mx = fmaxf(mx, __shfl_xor(mx, o, 64));
    __shared__ float red[8];
    if ((tid & 63) == 0) red[tid >> 6] = mx;
    __syncthreads();
    mx = fmaxf(fmaxf(red[0], red[1]), fmaxf(red[2], red[3]));
    float sum = 0.f;
#pragma unroll
    for (int i = 0; i < 16; i++) { v[i] = __expf(v[i] - mx); sum += v[i]; }
#pragma unroll
    for (int o = 32; o >= 1; o >>= 1) sum += __shfl_xor(sum, o, 64);
    if ((tid & 63) == 0) red[4 + (tid >> 6)] = sum;
    __syncthreads();
    const float inv = 1.0f / (red[4] + red[5] + red[6] + red[7]);

    const float4* brow = (const float4*)(bias + row * 4096 + tid * 16);
    unsigned o[8];
#pragma unroll
    for (int i = 0; i < 4; i++) {
        float4 b = brow[i];
        unsigned lo = f2bf(v[4 * i + 0] * inv + b.x);
        unsigned hi = f2bf(v[4 * i + 1] * inv + b.y);
        o[2 * i] = lo | (hi << 16);
        lo = f2bf(v[4 * i + 2] * inv + b.z);
        hi = f2bf(v[4 * i + 3] * inv + b.w);
        o[2 * i + 1] = lo | (hi << 16);
    }
    u16* arow = att + row * 4096 + tid * 16;
    *(uint4*)(arow)     = make_uint4(o[0], o[1], o[2], o[3]);
    *(uint4*)(arow + 8) = make_uint4(o[4], o[5], o[6], o[7]);
}

// ---------------------------------------------------------------------------
// Kernel 5: split-K=2: P[z] = att[:, z*2048:(z+1)*2048] @ vpT[:, z*2048:..]^T
// M=4096, N=1024, K=2048 per split. Grid (8, 32, 2) = 512 blocks.
// XCD-swizzled: default mapping put XCD = x%8 (one N-column per XCD), which
// streamed ALL of att (32 MB) through each 4 MB L2 -> 135 MB FETCH observed.
// Chunked swizzle gives each XCD 8 contiguous M-tiles x all N x one split:
// att rows XCD-exclusive (32 MB once) + vpT 4 MB/XCD -> ~64 MB total.
// ---------------------------------------------------------------------------
__global__ __launch_bounds__(256, 2)
void out_gemm(const u16* __restrict__ att, const u16* __restrict__ vpT,
              float* __restrict__ P)
{
    __shared__ __align__(16) u16 sA[8192];
    __shared__ __align__(16) u16 sB[8192];
    int bx, by, bz;
    xcd_swz(8, 32, bx, by, bz);
    const u16* A = att + bz * 2048;
    const u16* B = vpT + bz * 2048;
    float* O = P + (long)bz * 4096 * 1024;

    f32x4 acc[4][4] = {};
    gemm_core(A, B, 4096, 4096, 2048, by, bx, sA, sB, acc);

    const int lane = threadIdx.x & 63;
    const int wm   = (threadIdx.x >> 7) & 1;
    const int wn   = (threadIdx.x >> 6) & 1;
    const int m0 = by * 128 + wm * 64 + ((lane >> 4) << 2);
    const int n0 = bx * 128 + wn * 64 + (lane & 15);
#pragma unroll
    for (int mi = 0; mi < 4; mi++)
#pragma unroll
        for (int ni = 0; ni < 4; ni++) {
            const int gm = m0 + mi * 16;
            const int gn = n0 + ni * 16;
#pragma unroll
            for (int r = 0; r < 4; r++)
                O[(long)(gm + r) * 1024 + gn] = acc[mi][ni][r];
        }
}

// ---------------------------------------------------------------------------
// Kernel 6: out = P0 + P1  (fp32), 4096x1024
// ---------------------------------------------------------------------------
__global__ __launch_bounds__(256)
void addp(const float* __restrict__ P, float* __restrict__ O)
{
    long i = ((long)blockIdx.x * 256 + threadIdx.x) * 4;
    float4 a = *(const float4*)(P + i);
    float4 b = *(const float4*)(P + 4194304 + i);
    float4 r;
    r.x = a.x + b.x; r.y = a.y + b.y; r.z = a.z + b.z; r.w = a.w + b.w;
    *(float4*)(O + i) = r;
}

// ---------------------------------------------------------------------------
extern "C" void kernel_launch(void* const* d_in, const int* in_sizes, int n_in,
                              void* d_out, int out_size, void* d_ws, size_t ws_size,
                              hipStream_t stream)
{
    const float* q    = (const float*)d_in[0];
    const float* k    = (const float*)d_in[1];
    const float* v    = (const float*)d_in[2];
    const float* bias = (const float*)d_in[3];
    const float* Wq   = (const float*)d_in[4];
    const float* bq   = (const float*)d_in[5];
    const float* Wk   = (const float*)d_in[6];
    const float* bk   = (const float*)d_in[7];
    const float* Wv   = (const float*)d_in[8];
    const float* bv   = (const float*)d_in[9];
    float* out = (float*)d_out;

    uint8_t* ws = (uint8_t*)d_ws;
    const size_t MB = 1u << 20;
    // layout (118 MB), identical to the R5 known-good run:
    //   [0,8)    qb   [8,16) kb   [16,24) vb        (dead after proj/vproj)
    //   [24,26)  wqb  [26,28) wkb [28,30) wvb       (dead after proj/vproj)
    //   [30,38)  qp   [38,46) kp                    (dead after score_gemm)
    //   [46,54)  vpT
    //   [54,86)  S (bf16 scores, 32MB)              (dead after softmax)
    //   [0,32)   att (bf16, 32MB) -- aliases dead qb/kb/vb region
    //   [86,118) P (2x fp32 partials, 16MB each)
    u16* qb  = (u16*)(ws);
    u16* kb  = (u16*)(ws + 8 * MB);
    u16* vb  = (u16*)(ws + 16 * MB);
    u16* wqb = (u16*)(ws + 24 * MB);
    u16* wkb = (u16*)(ws + 26 * MB);
    u16* wvb = (u16*)(ws + 28 * MB);
    u16* qp  = (u16*)(ws + 30 * MB);
    u16* kp  = (u16*)(ws + 38 * MB);
    u16* vpT = (u16*)(ws + 46 * MB);
    u16* S   = (u16*)(ws + 54 * MB);
    u16* att = (u16*)(ws);
    float* P = (float*)(ws + 86 * MB);

    cast6<<<dim3(2048, 6), 256, 0, stream>>>(q, k, v, Wq, Wk, Wv,
                                             qb, kb, vb, wqb, wkb, wvb,
                                             4096 * 1024, 1024 * 1024);
    proj_gemm<<<dim3(8, 32, 2), 256, 0, stream>>>(qb, kb, vb, wqb, wkb, wvb,
                                                  bq, bk, bv, qp, kp, vpT);
    vproj_gemm<<<dim3(32, 8), 256, 0, stream>>>(wvb, vb, bv, vpT);
    score_gemm<<<dim3(32, 32), 256, 0, stream>>>(qp, kp, S);
    softmax_bias<<<dim3(4096), 256, 0, stream>>>(S, bias, att);
    out_gemm<<<dim3(8, 32, 2), 256, 0, stream>>>(att, vpT, P);
    addp<<<dim3(4096), 256, 0, stream>>>(P, out);
}

// Round 2
// 298.557 us; speedup vs baseline: 1.0293x; 1.0169x over previous
//
#include <hip/hip_runtime.h>
#include <hip/hip_bf16.h>
#include <stdint.h>

typedef unsigned short u16;
using bf16x8 = __attribute__((ext_vector_type(8))) __bf16;
using f32x4  = __attribute__((ext_vector_type(4))) float;

// fp32 -> bf16 (round-to-nearest-even), as raw bits
__device__ __forceinline__ u16 f2bf(float f) {
    union { float f; unsigned u; } a; a.f = f;
    unsigned u = a.u;
    u += 0x7fffu + ((u >> 16) & 1u);
    return (u16)(u >> 16);
}
__device__ __forceinline__ float bf2f(unsigned bits_hi16) {
    union { unsigned u; float f; } a; a.u = bits_hi16; return a.f;
}

// async global->LDS, 16 bytes per lane (global_load_lds_dwordx4)
__device__ __forceinline__ void gload_lds16(const void* g, void* l) {
    __builtin_amdgcn_global_load_lds(
        (const __attribute__((address_space(1))) void*)g,
        (__attribute__((address_space(3))) void*)l, 16, 0, 0);
}

// Bijective XCD-aware swizzle (T1); requires nwg % 8 == 0.
__device__ __forceinline__ void xcd_swz(int nx, int ny, int& x, int& y, int& z) {
    const int flat = (int)blockIdx.x + nx * ((int)blockIdx.y + ny * (int)blockIdx.z);
    const int cpx = (nx * ny * (int)gridDim.z) >> 3;  // chunk per XCD
    const int s = (flat & 7) * cpx + (flat >> 3);
    x = s % nx;
    const int t = s / nx;
    y = t % ny;
    z = t / ny;
}

// ---------------------------------------------------------------------------
// Legacy 128x128-tile bf16 GEMM core (m97 structure), C = A @ B^T.
// Still used by proj/vproj/out this round.
// ---------------------------------------------------------------------------
__device__ __forceinline__ void gemm_core(const u16* __restrict__ A,
                                          const u16* __restrict__ B,
                                          int lda, int ldb, int kLen,
                                          int bm, int bn,
                                          u16* sA, u16* sB,
                                          f32x4 acc[4][4])
{
    const int tid  = threadIdx.x;
    const int lane = tid & 63;
    const int wm   = (tid >> 7) & 1;
    const int wn   = (tid >> 6) & 1;

    const u16* Ag0 = A + (long)(bm * 128 + (tid >> 2)) * lda + (tid & 3) * 8;
    const u16* Ag1 = Ag0 + (long)64 * lda;
    const u16* Bg0 = B + (long)(bn * 128 + (tid >> 2)) * ldb + (tid & 3) * 8;
    const u16* Bg1 = Bg0 + (long)64 * ldb;
    u16* la = sA + tid * 8;
    u16* lb = sB + tid * 8;

    const int rfo  = (wm * 64 + (lane & 15)) * 32 + (lane >> 4) * 8;
    const int rfoB = (wn * 64 + (lane & 15)) * 32 + (lane >> 4) * 8;

    for (int k0 = 0; k0 < kLen; k0 += 64) {
        gload_lds16(Ag0 + k0, la);
        gload_lds16(Ag1 + k0, la + 2048);
        gload_lds16(Bg0 + k0, lb);
        gload_lds16(Bg1 + k0, lb + 2048);
        gload_lds16(Ag0 + k0 + 32, la + 4096);
        gload_lds16(Ag1 + k0 + 32, la + 6144);
        gload_lds16(Bg0 + k0 + 32, lb + 4096);
        gload_lds16(Bg1 + k0 + 32, lb + 6144);
        __syncthreads();
#pragma unroll
        for (int h = 0; h < 2; h++) {
            const u16* ra = sA + h * 4096 + rfo;
            const u16* rb = sB + h * 4096 + rfoB;
            bf16x8 af[4], bfr[4];
#pragma unroll
            for (int i = 0; i < 4; i++) af[i]  = *(const bf16x8*)(ra + i * 512);
#pragma unroll
            for (int i = 0; i < 4; i++) bfr[i] = *(const bf16x8*)(rb + i * 512);
#pragma unroll
            for (int mi = 0; mi < 4; mi++)
#pragma unroll
                for (int ni = 0; ni < 4; ni++)
                    acc[mi][ni] = __builtin_amdgcn_mfma_f32_16x16x32_bf16(
                        af[mi], bfr[ni], acc[mi][ni], 0, 0, 0);
        }
        __syncthreads();
    }
}

// ---------------------------------------------------------------------------
// Kernel 1: fp32 -> bf16 casts
// ---------------------------------------------------------------------------
__global__ __launch_bounds__(256)
void cast6(const float* __restrict__ q, const float* __restrict__ k,
           const float* __restrict__ v, const float* __restrict__ wq,
           const float* __restrict__ wk, const float* __restrict__ wv,
           u16* __restrict__ qb, u16* __restrict__ kb, u16* __restrict__ vb,
           u16* __restrict__ wqb, u16* __restrict__ wkb, u16* __restrict__ wvb,
           int nqkv, int nw)
{
    const int z = blockIdx.y;
    const float* s; u16* d; int n;
    switch (z) {
        case 0:  s = q;  d = qb;  n = nqkv; break;
        case 1:  s = k;  d = kb;  n = nqkv; break;
        case 2:  s = v;  d = vb;  n = nqkv; break;
        case 3:  s = wq; d = wqb; n = nw;   break;
        case 4:  s = wk; d = wkb; n = nw;   break;
        default: s = wv; d = wvb; n = nw;   break;
    }
    long i = ((long)blockIdx.x * 256 + threadIdx.x) * 8;
    if (i >= n) return;
    float4 a = *(const float4*)(s + i);
    float4 b = *(const float4*)(s + i + 4);
    ushort4 o0, o1;
    o0.x = f2bf(a.x); o0.y = f2bf(a.y); o0.z = f2bf(a.z); o0.w = f2bf(a.w);
    o1.x = f2bf(b.x); o1.y = f2bf(b.y); o1.z = f2bf(b.z); o1.w = f2bf(b.w);
    *(ushort4*)(d + i)     = o0;
    *(ushort4*)(d + i + 4) = o1;
}

// ---------------------------------------------------------------------------
// Kernel 2: QK projections
// ---------------------------------------------------------------------------
__global__ __launch_bounds__(256, 2)
void proj_gemm(const u16* __restrict__ qb, const u16* __restrict__ kb,
               const u16* __restrict__ vb, const u16* __restrict__ wqb,
               const u16* __restrict__ wkb, const u16* __restrict__ wvb,
               const float* __restrict__ bq, const float* __restrict__ bk,
               const float* __restrict__ bv,
               u16* __restrict__ qp, u16* __restrict__ kp, u16* __restrict__ vpT)
{
    __shared__ __align__(16) u16 sA[8192];
    __shared__ __align__(16) u16 sB[8192];
    int bx, by, bz;
    xcd_swz(8, 32, bx, by, bz);
    const int z = bz;
    const u16* A = (z == 0) ? qb : (z == 1) ? kb : vb;
    const u16* B = (z == 0) ? wqb : (z == 1) ? wkb : wvb;
    const float* bias = (z == 0) ? bq : (z == 1) ? bk : bv;
    u16* OUT = (z == 0) ? qp : (z == 1) ? kp : vpT;
    const float scale = (z == 0) ? 0.03125f : 1.0f;  // 1024^-0.5

    f32x4 acc[4][4] = {};
    gemm_core(A, B, 1024, 1024, 1024, by, bx, sA, sB, acc);

    const int lane = threadIdx.x & 63;
    const int wm   = (threadIdx.x >> 7) & 1;
    const int wn   = (threadIdx.x >> 6) & 1;
    const int m0 = by * 128 + wm * 64 + ((lane >> 4) << 2);
    const int n0 = bx * 128 + wn * 64 + (lane & 15);
#pragma unroll
    for (int mi = 0; mi < 4; mi++)
#pragma unroll
        for (int ni = 0; ni < 4; ni++) {
            const int gm = m0 + mi * 16;
            const int gn = n0 + ni * 16;
            const float bb = bias[gn];
#pragma unroll
            for (int r = 0; r < 4; r++) {
                float val = (acc[mi][ni][r] + bb) * scale;
                if (z < 2) OUT[(long)(gm + r) * 1024 + gn] = f2bf(val);
                else       OUT[(long)gn * 4096 + gm + r]   = f2bf(val);
            }
        }
}

// ---------------------------------------------------------------------------
// Kernel 2b: vpT = Wv @ v^T + bv (per-row)  [1024 x 4096]
// ---------------------------------------------------------------------------
__global__ __launch_bounds__(256, 2)
void vproj_gemm(const u16* __restrict__ wvb, const u16* __restrict__ vb,
                const float* __restrict__ bv, u16* __restrict__ vpT)
{
    __shared__ __align__(16) u16 sA[8192];
    __shared__ __align__(16) u16 sB[8192];
    f32x4 acc[4][4] = {};
    gemm_core(wvb, vb, 1024, 1024, 1024, blockIdx.y, blockIdx.x, sA, sB, acc);

    const int lane = threadIdx.x & 63;
    const int wm   = (threadIdx.x >> 7) & 1;
    const int wn   = (threadIdx.x >> 6) & 1;
    const int m0 = blockIdx.y * 128 + wm * 64 + ((lane >> 4) << 2);
    const int n0 = blockIdx.x * 128 + wn * 64 + (lane & 15);
#pragma unroll
    for (int mi = 0; mi < 4; mi++)
#pragma unroll
        for (int ni = 0; ni < 4; ni++) {
            const int gm = m0 + mi * 16;
            const int gn = n0 + ni * 16;
#pragma unroll
            for (int r = 0; r < 4; r++)
                vpT[(long)(gm + r) * 4096 + gn] = f2bf(acc[mi][ni][r] + bv[gm + r]);
        }
}

// ---------------------------------------------------------------------------
// Kernel 3 (NEW): scores = qp @ kp^T -> bf16 S. 256x256 tile, 8 waves,
// 4-phase register-decoupled pipeline with counted vmcnt (T2+T3+T4+T5).
//
// LDS (128 KB): 2 K-tile buffers x { A:[2 kh][256 rows][32 cols], B: same }.
// k-half subtile row = 64 B. Bank swizzle: 16B-slot ^= (row>>1)&3, applied
// as pre-swizzled GLOBAL source (gload_lds dest must be linear) + same XOR
// on ds_read (per-lane it folds to the constant (l>>4)^((l>>1)&3)).
//
// Per K-tile t (buffer b = t&1):
//  ph1: ds_read all ks0 frags (8 A + 4 B) ; MFMA mi0-3 x ni0-3 x ks0
//       lgkmcnt(0) ; barrier            (kh0 region now dead to all waves)
//  ph2: stage kh0 of tile t+2 -> buffer b ; MFMA mi4-7 ks0 ; barrier
//  ph3: ds_read ks1 frags ; MFMA mi0-3 ks1 ; lgkmcnt(0) ; barrier
//  ph4: stage kh1 of t+2 ; MFMA mi4-7 ks1 ; vmcnt(8) ; barrier
// vmcnt(8) = 2 loads x 4 half-tiles in flight (tile t+2); per-wave staging
// is symmetric, so each wave's own count implies tile t+1 fully resident.
// ---------------------------------------------------------------------------
__global__ __launch_bounds__(512, 2)
void score_gemm256(const u16* __restrict__ qp, const u16* __restrict__ kp,
                   u16* __restrict__ S)
{
    __shared__ __align__(16) u16 lds[65536];  // 128 KB

    // XCD swizzle, grid 16x16 = 256 blocks
    const int flat = (int)blockIdx.x + ((int)blockIdx.y << 4);
    const int sfl = (flat & 7) * 32 + (flat >> 3);
    const int bx = sfl & 15;   // N tile
    const int by = sfl >> 4;   // M tile

    const int tid = (int)threadIdx.x;
    const int l  = tid & 63;
    const int w  = tid >> 6;          // wave 0..7
    const int wm = w >> 2;            // 0..1
    const int wn = w & 3;             // 0..3

    const int lda = 1024, ldb = 1024;
    const int T = 16;                 // K=1024 / 64

    // staging: wave w, instr i stages rows w*32+i*16+(l>>2), 64B/row,
    // source col pre-swizzled so linear LDS holds swizzled content
    const int srcswz = 8 * ((l & 3) ^ ((l >> 3) & 3));
    const u16* pA = qp + (long)(by * 256 + w * 32 + (l >> 2)) * lda + srcswz;
    const u16* pB = kp + (long)(bx * 256 + w * 32 + (l >> 2)) * ldb + srcswz;
    // LDS dest base (u16 idx): + i*512, + kh*8192, +16384 for B, + buf
    const int dstbase = w * 1024 + l * 8;

    // fragment read bases (swizzled slot is constant per lane)
    const int fsw = 8 * ((l >> 4) ^ ((l >> 1) & 3));
    const int fA = (wm * 128 + (l & 15)) * 32 + fsw;
    const int fB = (wn * 64  + (l & 15)) * 32 + fsw;

    f32x4 acc[8][4] = {};

    // ---- prologue: stage tile0 -> buf0, tile1 -> buf1 ----
    {
        u16* d0 = lds + dstbase;
        gload_lds16(pA,                d0);
        gload_lds16(pA + 16 * lda,     d0 + 512);
        gload_lds16(pB,                d0 + 16384);
        gload_lds16(pB + 16 * ldb,     d0 + 16384 + 512);
        gload_lds16(pA + 32,           d0 + 8192);
        gload_lds16(pA + 16 * lda + 32, d0 + 8192 + 512);
        gload_lds16(pB + 32,           d0 + 24576);
        gload_lds16(pB + 16 * ldb + 32, d0 + 24576 + 512);
        const u16* a1 = pA + 64;
        const u16* b1 = pB + 64;
        u16* d1 = lds + 32768 + dstbase;
        gload_lds16(a1,                d1);
        gload_lds16(a1 + 16 * lda,     d1 + 512);
        gload_lds16(b1,                d1 + 16384);
        gload_lds16(b1 + 16 * ldb,     d1 + 16384 + 512);
        gload_lds16(a1 + 32,           d1 + 8192);
        gload_lds16(a1 + 16 * lda + 32, d1 + 8192 + 512);
        gload_lds16(b1 + 32,           d1 + 24576);
        gload_lds16(b1 + 16 * ldb + 32, d1 + 24576 + 512);
        asm volatile("s_waitcnt vmcnt(8)" ::: "memory");  // tile0 resident
        __builtin_amdgcn_s_barrier();
    }

    // ---- main loop ----
    for (int t = 0; t < T; ++t) {
        const int buf = (t & 1) << 15;          // u16 offset
        const u16* Ar = lds + buf;
        const u16* Br = lds + buf + 16384;
        const bool st = (t + 2) < T;
        const u16* sa = pA + (t + 2) * 64;
        const u16* sb = pB + (t + 2) * 64;
        u16* d = lds + buf + dstbase;

        bf16x8 af[8], bfr[4];

        // ---------- phase 1: ks0 reads + MFMA mi0-3 ----------
#pragma unroll
        for (int mi = 0; mi < 8; mi++)
            af[mi] = *(const bf16x8*)(Ar + fA + mi * 512);
#pragma unroll
        for (int ni = 0; ni < 4; ni++)
            bfr[ni] = *(const bf16x8*)(Br + fB + ni * 512);
        __builtin_amdgcn_s_setprio(1);
#pragma unroll
        for (int mi = 0; mi < 4; mi++)
#pragma unroll
            for (int ni = 0; ni < 4; ni++)
                acc[mi][ni] = __builtin_amdgcn_mfma_f32_16x16x32_bf16(
                    af[mi], bfr[ni], acc[mi][ni], 0, 0, 0);
        __builtin_amdgcn_s_setprio(0);
        asm volatile("s_waitcnt lgkmcnt(0)" ::: "memory");  // all 12 reads done
        __builtin_amdgcn_s_barrier();

        // ---------- phase 2: stage kh0(t+2) + MFMA mi4-7 ks0 ----------
        if (st) {
            gload_lds16(sa,            d);
            gload_lds16(sa + 16 * lda, d + 512);
            gload_lds16(sb,            d + 16384);
            gload_lds16(sb + 16 * ldb, d + 16384 + 512);
        }
        __builtin_amdgcn_s_setprio(1);
#pragma unroll
        for (int mi = 4; mi < 8; mi++)
#pragma unroll
            for (int ni = 0; ni < 4; ni++)
                acc[mi][ni] = __builtin_amdgcn_mfma_f32_16x16x32_bf16(
                    af[mi], bfr[ni], acc[mi][ni], 0, 0, 0);
        __builtin_amdgcn_s_setprio(0);
        __builtin_amdgcn_s_barrier();

        // ---------- phase 3: ks1 reads + MFMA mi0-3 ----------
#pragma unroll
        for (int mi = 0; mi < 8; mi++)
            af[mi] = *(const bf16x8*)(Ar + 8192 + fA + mi * 512);
#pragma unroll
        for (int ni = 0; ni < 4; ni++)
            bfr[ni] = *(const bf16x8*)(Br + 8192 + fB + ni * 512);
        __builtin_amdgcn_s_setprio(1);
#pragma unroll
        for (int mi = 0; mi < 4; mi++)
#pragma unroll
            for (int ni = 0; ni < 4; ni++)
                acc[mi][ni] = __builtin_amdgcn_mfma_f32_16x16x32_bf16(
                    af[mi], bfr[ni], acc[mi][ni], 0, 0, 0);
        __builtin_amdgcn_s_setprio(0);
        asm volatile("s_waitcnt lgkmcnt(0)" ::: "memory");
        __builtin_amdgcn_s_barrier();

        // ---------- phase 4: stage kh1(t+2) + MFMA mi4-7 ks1 ----------
        if (st) {
            gload_lds16(sa + 32,            d + 8192);
            gload_lds16(sa + 16 * lda + 32, d + 8192 + 512);
            gload_lds16(sb + 32,            d + 24576);
            gload_lds16(sb + 16 * ldb + 32, d + 24576 + 512);
        }
        __builtin_amdgcn_s_setprio(1);
#pragma unroll
        for (int mi = 4; mi < 8; mi++)
#pragma unroll
            for (int ni = 0; ni < 4; ni++)
                acc[mi][ni] = __builtin_amdgcn_mfma_f32_16x16x32_bf16(
                    af[mi], bfr[ni], acc[mi][ni], 0, 0, 0);
        __builtin_amdgcn_s_setprio(0);
        if (st) asm volatile("s_waitcnt vmcnt(8)" ::: "memory");
        else    asm volatile("s_waitcnt vmcnt(0)" ::: "memory");
        __builtin_amdgcn_s_barrier();
    }

    // ---- epilogue ----
    const int gm0 = by * 256 + wm * 128 + ((l >> 4) << 2);
    const int gn0 = bx * 256 + wn * 64 + (l & 15);
#pragma unroll
    for (int mi = 0; mi < 8; mi++)
#pragma unroll
        for (int ni = 0; ni < 4; ni++) {
            const int gm = gm0 + mi * 16;
            const int gn = gn0 + ni * 16;
#pragma unroll
            for (int r = 0; r < 4; r++)
                S[(long)(gm + r) * 4096 + gn] = f2bf(acc[mi][ni][r]);
        }
}

// ---------------------------------------------------------------------------
// Kernel 4: att = softmax(S_bf16, axis=-1) + bias, cast to bf16. Block per row.
// ---------------------------------------------------------------------------
__global__ __launch_bounds__(256)
void softmax_bias(const u16* __restrict__ S, const float* __restrict__ bias,
                  u16* __restrict__ att)
{
    const long row = blockIdx.x;
    const int tid = threadIdx.x;
    const u16* srow = S + row * 4096 + tid * 16;

    float v[16];
    {
        uint4 a = *(const uint4*)(srow);
        uint4 b = *(const uint4*)(srow + 8);
        unsigned w[8] = {a.x, a.y, a.z, a.w, b.x, b.y, b.z, b.w};
#pragma unroll
        for (int i = 0; i < 8; i++) {
            v[2 * i]     = bf2f(w[i] << 16);
            v[2 * i + 1] = bf2f(w[i] & 0xffff0000u);
        }
    }
    float mx = v[0];
#pragma unroll
    for (int i = 1; i < 16; i++) mx = fmaxf(mx, v[i]);
#pragma unroll
    for (int o = 32; o >= 1; o >>= 1) mx = fmaxf(mx, __shfl_xor(mx, o, 64));
    __shared__ float red[8];
    if ((tid & 63) == 0) red[tid >> 6] = mx;
    __syncthreads();
    mx = fmaxf(fmaxf(red[0], red[1]), fmaxf(red[2], red[3]));
    float sum = 0.f;
#pragma unroll
    for (int i = 0; i < 16; i++) { v[i] = __expf(v[i] - mx); sum += v[i]; }
#pragma unroll
    for (int o = 32; o >= 1; o >>= 1) sum += __shfl_xor(sum, o, 64);
    if ((tid & 63) == 0) red[4 + (tid >> 6)] = sum;
    __syncthreads();
    const float inv = 1.0f / (red[4] + red[5] + red[6] + red[7]);

    const float4* brow = (const float4*)(bias + row * 4096 + tid * 16);
    unsigned o[8];
#pragma unroll
    for (int i = 0; i < 4; i++) {
        float4 b = brow[i];
        unsigned lo = f2bf(v[4 * i + 0] * inv + b.x);
        unsigned hi = f2bf(v[4 * i + 1] * inv + b.y);
        o[2 * i] = lo | (hi << 16);
        lo = f2bf(v[4 * i + 2] * inv + b.z);
        hi = f2bf(v[4 * i + 3] * inv + b.w);
        o[2 * i + 1] = lo | (hi << 16);
    }
    u16* arow = att + row * 4096 + tid * 16;
    *(uint4*)(arow)     = make_uint4(o[0], o[1], o[2], o[3]);
    *(uint4*)(arow + 8) = make_uint4(o[4], o[5], o[6], o[7]);
}

// ---------------------------------------------------------------------------
// Kernel 5: split-K=2: P[z] = att[:, z*2048:(z+1)*2048] @ vpT[:, z*2048:..]^T
// XCD-swizzled (R1: FETCH 135->33 MB).
// ---------------------------------------------------------------------------
__global__ __launch_bounds__(256, 2)
void out_gemm(const u16* __restrict__ att, const u16* __restrict__ vpT,
              float* __restrict__ P)
{
    __shared__ __align__(16) u16 sA[8192];
    __shared__ __align__(16) u16 sB[8192];
    int bx, by, bz;
    xcd_swz(8, 32, bx, by, bz);
    const u16* A = att + bz * 2048;
    const u16* B = vpT + bz * 2048;
    float* O = P + (long)bz * 4096 * 1024;

    f32x4 acc[4][4] = {};
    gemm_core(A, B, 4096, 4096, 2048, by, bx, sA, sB, acc);

    const int lane = threadIdx.x & 63;
    const int wm   = (threadIdx.x >> 7) & 1;
    const int wn   = (threadIdx.x >> 6) & 1;
    const int m0 = by * 128 + wm * 64 + ((lane >> 4) << 2);
    const int n0 = bx * 128 + wn * 64 + (lane & 15);
#pragma unroll
    for (int mi = 0; mi < 4; mi++)
#pragma unroll
        for (int ni = 0; ni < 4; ni++) {
            const int gm = m0 + mi * 16;
            const int gn = n0 + ni * 16;
#pragma unroll
            for (int r = 0; r < 4; r++)
                O[(long)(gm + r) * 1024 + gn] = acc[mi][ni][r];
        }
}

// ---------------------------------------------------------------------------
// Kernel 6: out = P0 + P1  (fp32), 4096x1024
// ---------------------------------------------------------------------------
__global__ __launch_bounds__(256)
void addp(const float* __restrict__ P, float* __restrict__ O)
{
    long i = ((long)blockIdx.x * 256 + threadIdx.x) * 4;
    float4 a = *(const float4*)(P + i);
    float4 b = *(const float4*)(P + 4194304 + i);
    float4 r;
    r.x = a.x + b.x; r.y = a.y + b.y; r.z = a.z + b.z; r.w = a.w + b.w;
    *(float4*)(O + i) = r;
}

// ---------------------------------------------------------------------------
extern "C" void kernel_launch(void* const* d_in, const int* in_sizes, int n_in,
                              void* d_out, int out_size, void* d_ws, size_t ws_size,
                              hipStream_t stream)
{
    const float* q    = (const float*)d_in[0];
    const float* k    = (const float*)d_in[1];
    const float* v    = (const float*)d_in[2];
    const float* bias = (const float*)d_in[3];
    const float* Wq   = (const float*)d_in[4];
    const float* bq   = (const float*)d_in[5];
    const float* Wk   = (const float*)d_in[6];
    const float* bk   = (const float*)d_in[7];
    const float* Wv   = (const float*)d_in[8];
    const float* bv   = (const float*)d_in[9];
    float* out = (float*)d_out;

    uint8_t* ws = (uint8_t*)d_ws;
    const size_t MB = 1u << 20;
    u16* qb  = (u16*)(ws);
    u16* kb  = (u16*)(ws + 8 * MB);
    u16* vb  = (u16*)(ws + 16 * MB);
    u16* wqb = (u16*)(ws + 24 * MB);
    u16* wkb = (u16*)(ws + 26 * MB);
    u16* wvb = (u16*)(ws + 28 * MB);
    u16* qp  = (u16*)(ws + 30 * MB);
    u16* kp  = (u16*)(ws + 38 * MB);
    u16* vpT = (u16*)(ws + 46 * MB);
    u16* S   = (u16*)(ws + 54 * MB);
    u16* att = (u16*)(ws);
    float* P = (float*)(ws + 86 * MB);

    cast6<<<dim3(2048, 6), 256, 0, stream>>>(q, k, v, Wq, Wk, Wv,
                                             qb, kb, vb, wqb, wkb, wvb,
                                             4096 * 1024, 1024 * 1024);
    proj_gemm<<<dim3(8, 32, 2), 256, 0, stream>>>(qb, kb, vb, wqb, wkb, wvb,
                                                  bq, bk, bv, qp, kp, vpT);
    vproj_gemm<<<dim3(32, 8), 256, 0, stream>>>(wvb, vb, bv, vpT);
    score_gemm256<<<dim3(16, 16), 512, 0, stream>>>(qp, kp, S);
    softmax_bias<<<dim3(4096), 256, 0, stream>>>(S, bias, att);
    out_gemm<<<dim3(8, 32, 2), 256, 0, stream>>>(att, vpT, P);
    addp<<<dim3(4096), 256, 0, stream>>>(P, out);
}